// Round 9
// baseline (46.921 us; speedup 1.0000x reference)
//
#include <hip/hip_runtime.h>
#include <math.h>

// Problem constants (from reference setup_inputs)
#define BATCH 16
#define HIN   224
#define WIN   224
#define CCH   32
#define FDIM  128
#define HOUT  224
#define WOUT  224

#define PIX_PER_BATCH (HOUT * WOUT)               // 50176
#define BLOCK 256
#define ITEMS_PER_THREAD 4
#define ITEMS_PER_BLOCK (BLOCK * ITEMS_PER_THREAD)       // 1024 items = 128 pixels
#define PIX_PER_BLOCK (ITEMS_PER_BLOCK / 8)              // 128
#define BLOCKS_PER_BATCH (PIX_PER_BATCH / PIX_PER_BLOCK) // 392
#define NBLOCKS (BATCH * BLOCKS_PER_BATCH)        // 6272
#define NXCD 8
#define BLOCKS_PER_XCD (NBLOCKS / NXCD)           // 784 = exactly 2 batches

typedef float f32x4 __attribute__((ext_vector_type(4)));

// Single fused kernel, attempt 4.
// R2/R6/R8 fusions all collapsed to VGPR 16/36/36: the machine scheduler's
// pressure-MINIMIZING heuristic serializes the 16 tap loads when the theta
// preamble lengthens the dep chains (launch_bounds(256,1) proved the budget
// isn't the issue). Fix: an empty inline-asm pin with all 16 f32x4 results
// as "+v" operands — forces all 64 data VGPRs live at one point, so the
// scheduler must cluster the 16 loads (one vmcnt wait) and regalloc must
// allocate them. No-op for semantics.
__global__ __launch_bounds__(BLOCK, 1) void st_fused_kernel(
        const float* __restrict__ im,
        const float* __restrict__ tf,
        const float* __restrict__ Wm,
        const float* __restrict__ bv,
        float* __restrict__ out) {

    int bid = blockIdx.x;
    int nb  = (bid & (NXCD - 1)) * BLOCKS_PER_XCD + (bid >> 3);

    int b = nb / BLOCKS_PER_BATCH;             // batch of this block

    // ---- in-wave theta (identical result in every wave) ----
    int lane = (int)(threadIdx.x & 63);
    int j    = lane & 7;                       // 0..7, 6 used
    int c    = lane >> 3;                      // 0..7 chunk
    int jj   = (j < 6) ? j : 0;                // clamp to avoid OOB W reads

    const float* row = tf + b * FDIM;
    float acc = 0.0f;
#pragma unroll
    for (int m = 0; m < 16; ++m) {
        int k = c * 16 + m;
        acc += row[k] * Wm[k * 6 + jj];
    }
    acc += __shfl_xor(acc, 8);
    acc += __shfl_xor(acc, 16);
    acc += __shfl_xor(acc, 32);
    float thv = tanhf(acc + bv[jj]);           // lanes 0..5 hold theta_0..5

    float t0 = __shfl(thv, 0);
    float t1 = __shfl(thv, 1);
    float t2 = __shfl(thv, 2);
    float t3 = __shfl(thv, 3);
    float t4 = __shfl(thv, 4);
    float t5 = __shfl(thv, 5);

    // ---- bilinear sampling ----
    const f32x4* imf4 = (const f32x4*)im;
    f32x4* of4 = (f32x4*)out;
    unsigned ibase = (unsigned)b * (unsigned)(HIN * WIN * 8);

    int base = nb * ITEMS_PER_BLOCK + (int)threadIdx.x;

    unsigned addr[ITEMS_PER_THREAD][4];
    float    wgt[ITEMS_PER_THREAD][4];

#pragma unroll
    for (int u = 0; u < ITEMS_PER_THREAD; ++u) {
        int i  = base + u * BLOCK;             // global work item
        int p  = i >> 3;                       // output pixel
        int c4 = i & 7;                        // float4 chunk within pixel

        int rem = p - b * PIX_PER_BATCH;
        int ho  = rem / WOUT;
        int wo  = rem - ho * WOUT;

        float x_t = -1.0f + (2.0f * (float)wo) / (float)(WOUT - 1);
        float y_t = -1.0f + (2.0f * (float)ho) / (float)(HOUT - 1);

        float xs = t0 * x_t + t1 * y_t + t2;
        float ys = t3 * x_t + t4 * y_t + t5;

        float xp = (xs + 1.0f) * (0.5f * (float)WIN);
        float yp = (ys + 1.0f) * (0.5f * (float)HIN);

        int x0 = (int)floorf(xp);
        int y0 = (int)floorf(yp);
        int x1 = x0 + 1;
        int y1 = y0 + 1;

        x0 = min(max(x0, 0), WIN - 1);
        x1 = min(max(x1, 0), WIN - 1);
        y0 = min(max(y0, 0), HIN - 1);
        y1 = min(max(y1, 0), HIN - 1);

        float x0f = (float)x0, x1f = (float)x1;
        float y0f = (float)y0, y1f = (float)y1;

        wgt[u][0] = (x1f - xp) * (y1f - yp);   // wa
        wgt[u][1] = (x1f - xp) * (yp - y0f);   // wb
        wgt[u][2] = (xp - x0f) * (y1f - yp);   // wc
        wgt[u][3] = (xp - x0f) * (yp - y0f);   // wd

        addr[u][0] = ibase + (unsigned)(y0 * WIN + x0) * 8u + (unsigned)c4;
        addr[u][1] = ibase + (unsigned)(y1 * WIN + x0) * 8u + (unsigned)c4;
        addr[u][2] = ibase + (unsigned)(y0 * WIN + x1) * 8u + (unsigned)c4;
        addr[u][3] = ibase + (unsigned)(y1 * WIN + x1) * 8u + (unsigned)c4;
    }

    // issue all 16 loads back-to-back
    f32x4 v[ITEMS_PER_THREAD][4];
#pragma unroll
    for (int u = 0; u < ITEMS_PER_THREAD; ++u) {
#pragma unroll
        for (int t = 0; t < 4; ++t) {
            v[u][t] = imf4[addr[u][t]];
        }
    }

    // pin: all 16 results live here -> scheduler must cluster the loads,
    // regalloc must hold 64 data VGPRs (defeats pressure-min serialization)
    asm volatile(""
        : "+v"(v[0][0]), "+v"(v[0][1]), "+v"(v[0][2]), "+v"(v[0][3]),
          "+v"(v[1][0]), "+v"(v[1][1]), "+v"(v[1][2]), "+v"(v[1][3]),
          "+v"(v[2][0]), "+v"(v[2][1]), "+v"(v[2][2]), "+v"(v[2][3]),
          "+v"(v[3][0]), "+v"(v[3][1]), "+v"(v[3][2]), "+v"(v[3][3]));

#pragma unroll
    for (int u = 0; u < ITEMS_PER_THREAD; ++u) {
        f32x4 o = wgt[u][0] * v[u][0] + wgt[u][1] * v[u][1]
                + wgt[u][2] * v[u][2] + wgt[u][3] * v[u][3];
        // nontemporal: output is write-only, keep L2 for gather taps
        __builtin_nontemporal_store(o, &of4[base + u * BLOCK]);
    }
}

extern "C" void kernel_launch(void* const* d_in, const int* in_sizes, int n_in,
                              void* d_out, int out_size, void* d_ws, size_t ws_size,
                              hipStream_t stream) {
    const float* x  = (const float*)d_in[0];   // (16,224,224,32) f32
    const float* tf = (const float*)d_in[1];   // (16,128) f32
    const float* Wm = (const float*)d_in[2];   // (128,6) f32
    const float* bv = (const float*)d_in[3];   // (6,) f32
    float* out = (float*)d_out;                // (16,224,224,32) f32

    st_fused_kernel<<<NBLOCKS, BLOCK, 0, stream>>>(x, tf, Wm, bv, out);
}

// Round 10
// 32.947 us; speedup vs baseline: 1.4241x; 1.4241x over previous
//
#include <hip/hip_runtime.h>
#include <math.h>

// Problem constants (from reference setup_inputs)
#define BATCH 16
#define HIN   224
#define WIN   224
#define CCH   32
#define FDIM  128
#define HOUT  224
#define WOUT  224

#define PIX_PER_BATCH (HOUT * WOUT)               // 50176
#define BLOCK 256
#define ITEMS_PER_THREAD 4
#define ITEMS_PER_BLOCK (BLOCK * ITEMS_PER_THREAD)       // 1024 items = 128 pixels
#define PIX_PER_BLOCK (ITEMS_PER_BLOCK / 8)              // 128
#define BLOCKS_PER_BATCH (PIX_PER_BATCH / PIX_PER_BLOCK) // 392
#define NBLOCKS (BATCH * BLOCKS_PER_BATCH)        // 6272
#define NXCD 8
#define BLOCKS_PER_XCD (NBLOCKS / NXCD)           // 784 = exactly 2 batches

typedef float f32x4 __attribute__((ext_vector_type(4)));

// Two-kernel structure is deliberate and final:
// fusing theta into the sampler makes EVERY wave (25088) re-gather the same
// ~3.3KB of tf/W with per-lane loads -> hot-L2-line contention storm at every
// block start -> all four fusion attempts ran ~2x slower (87/70/71/67 us)
// regardless of VGPR/pinning. The 96-wave theta dispatch broadcasts 24B/batch
// through memory for ~4us total; that is the cheap direction.

// ---------------- Kernel 1: theta = tanh(theta_feat @ W + b) ----------------
// One wave per (batch, j) output: 96 waves. 2 elements/lane + butterfly reduce.
__global__ void st_theta_kernel(const float* __restrict__ tf,
                                const float* __restrict__ Wm,
                                const float* __restrict__ bv,
                                float* __restrict__ theta) {
    int wid  = (int)((blockIdx.x * blockDim.x + threadIdx.x) >> 6);
    int lane = (int)(threadIdx.x & 63);
    if (wid >= BATCH * 6) return;
    int bi = wid / 6;
    int j  = wid - bi * 6;
    const float* row = tf + bi * FDIM;
    float acc = row[lane] * Wm[lane * 6 + j]
              + row[lane + 64] * Wm[(lane + 64) * 6 + j];
    acc += __shfl_xor(acc, 32);
    acc += __shfl_xor(acc, 16);
    acc += __shfl_xor(acc, 8);
    acc += __shfl_xor(acc, 4);
    acc += __shfl_xor(acc, 2);
    acc += __shfl_xor(acc, 1);
    if (lane == 0) theta[wid] = tanhf(acc + bv[j]);
}

// ---------------- Kernel 2: bilinear sampling ----------------
// 4 items/thread: 16 independent tap loads in flight, 32-bit element offsets.
// NT stores (write-only stream). XCD chunked swizzle: XCD k owns 784
// consecutive blocks = exactly 2 batches -> input-row reuse stays in that
// XCD's 4MB L2 (+37% vs round-robin, measured R1->R3).
__global__ __launch_bounds__(BLOCK) void st_sample_kernel(
        const float* __restrict__ im,
        const float* __restrict__ theta,
        float* __restrict__ out) {

    int bid = blockIdx.x;
    int nb  = (bid & (NXCD - 1)) * BLOCKS_PER_XCD + (bid >> 3);

    int b = nb / BLOCKS_PER_BATCH;             // batch of this block

    // uniform theta for the batch (scalar-cached)
    const float* th = theta + b * 6;
    float t0 = th[0], t1 = th[1], t2 = th[2];
    float t3 = th[3], t4 = th[4], t5 = th[5];

    const f32x4* imf4 = (const f32x4*)im;
    f32x4* of4 = (f32x4*)out;
    unsigned ibase = (unsigned)b * (unsigned)(HIN * WIN * 8);

    int base = nb * ITEMS_PER_BLOCK + (int)threadIdx.x;

    unsigned addr[ITEMS_PER_THREAD][4];
    float    wgt[ITEMS_PER_THREAD][4];

#pragma unroll
    for (int u = 0; u < ITEMS_PER_THREAD; ++u) {
        int i  = base + u * BLOCK;             // global work item
        int p  = i >> 3;                       // output pixel
        int c4 = i & 7;                        // float4 chunk within pixel

        int rem = p - b * PIX_PER_BATCH;
        int ho  = rem / WOUT;
        int wo  = rem - ho * WOUT;

        float x_t = -1.0f + (2.0f * (float)wo) / (float)(WOUT - 1);
        float y_t = -1.0f + (2.0f * (float)ho) / (float)(HOUT - 1);

        float xs = t0 * x_t + t1 * y_t + t2;
        float ys = t3 * x_t + t4 * y_t + t5;

        float xp = (xs + 1.0f) * (0.5f * (float)WIN);
        float yp = (ys + 1.0f) * (0.5f * (float)HIN);

        int x0 = (int)floorf(xp);
        int y0 = (int)floorf(yp);
        int x1 = x0 + 1;
        int y1 = y0 + 1;

        // clip ints first; weights use the clipped coords (matches reference)
        x0 = min(max(x0, 0), WIN - 1);
        x1 = min(max(x1, 0), WIN - 1);
        y0 = min(max(y0, 0), HIN - 1);
        y1 = min(max(y1, 0), HIN - 1);

        float x0f = (float)x0, x1f = (float)x1;
        float y0f = (float)y0, y1f = (float)y1;

        wgt[u][0] = (x1f - xp) * (y1f - yp);   // wa
        wgt[u][1] = (x1f - xp) * (yp - y0f);   // wb
        wgt[u][2] = (xp - x0f) * (y1f - yp);   // wc
        wgt[u][3] = (xp - x0f) * (yp - y0f);   // wd

        addr[u][0] = ibase + (unsigned)(y0 * WIN + x0) * 8u + (unsigned)c4;
        addr[u][1] = ibase + (unsigned)(y1 * WIN + x0) * 8u + (unsigned)c4;
        addr[u][2] = ibase + (unsigned)(y0 * WIN + x1) * 8u + (unsigned)c4;
        addr[u][3] = ibase + (unsigned)(y1 * WIN + x1) * 8u + (unsigned)c4;
    }

    // issue all 16 loads back-to-back (independent -> 16 outstanding vmem)
    f32x4 v[ITEMS_PER_THREAD][4];
#pragma unroll
    for (int u = 0; u < ITEMS_PER_THREAD; ++u) {
#pragma unroll
        for (int t = 0; t < 4; ++t) {
            v[u][t] = imf4[addr[u][t]];
        }
    }

#pragma unroll
    for (int u = 0; u < ITEMS_PER_THREAD; ++u) {
        f32x4 o = wgt[u][0] * v[u][0] + wgt[u][1] * v[u][1]
                + wgt[u][2] * v[u][2] + wgt[u][3] * v[u][3];
        // nontemporal: output is write-only, keep L2 for gather taps
        __builtin_nontemporal_store(o, &of4[base + u * BLOCK]);
    }
}

extern "C" void kernel_launch(void* const* d_in, const int* in_sizes, int n_in,
                              void* d_out, int out_size, void* d_ws, size_t ws_size,
                              hipStream_t stream) {
    const float* x  = (const float*)d_in[0];   // (16,224,224,32) f32
    const float* tf = (const float*)d_in[1];   // (16,128) f32
    const float* Wm = (const float*)d_in[2];   // (128,6) f32
    const float* bv = (const float*)d_in[3];   // (6,) f32
    float* out = (float*)d_out;                // (16,224,224,32) f32

    float* theta = (float*)d_ws;               // 96 floats scratch

    st_theta_kernel<<<24, 256, 0, stream>>>(tf, Wm, bv, theta);
    st_sample_kernel<<<NBLOCKS, BLOCK, 0, stream>>>(x, theta, out);
}